// Round 12
// baseline (136.452 us; speedup 1.0000x reference)
//
#include <hip/hip_runtime.h>
#include <math.h>

#define NPTS 4096
#define DD   128
#define NCH  24
#define NHID 5
#define PPB  4            // points per block (= quad)
#define BS   256
#define WP8  17           // jet plane row stride in half8 units (136 fp16)
#define WPW  68           // jet plane row stride in u32 units
#define PLSZ 26112        // jet plane: 96 rows x 272 B
#define OSM_OFF 26112     // Osm after the single plane
// jet row for (point p, channel c)
#define ROWM(p,c) (16*((c)>>2) + 4*(p) + ((c)&3))

typedef __attribute__((ext_vector_type(8))) _Float16 half8;
typedef __attribute__((ext_vector_type(2))) __fp16 fp16x2;
typedef __attribute__((ext_vector_type(4))) float f32x4;
typedef __attribute__((ext_vector_type(2))) float f32x2;

// channel scales: ch0-4,23: 1; ch5-13 (2nd): 2^-10; ch14-22 (3rd): 2^-16
#define SS_INV 1024.0f
#define ST_INV 65536.0f

static __device__ __forceinline__ unsigned short f2h_bits(float x) {
  _Float16 h = (_Float16)x; unsigned short u; __builtin_memcpy(&u, &h, 2); return u;
}
static __device__ __forceinline__ unsigned pk2(float a, float b) {
  fp16x2 h = __builtin_amdgcn_cvt_pkrtz(a, b);   // 1 inst, packs 2 fp16 (RTZ)
  unsigned u; __builtin_memcpy(&u, &h, 4); return u;
}

// ---------------- threefry2x32 (matches JAX's PRNG) ----------------
static __device__ __forceinline__ void tf2x32(unsigned k0, unsigned k1,
                                              unsigned x0, unsigned x1,
                                              unsigned &o0, unsigned &o1) {
  unsigned ks2 = 0x1BD11BDAu ^ k0 ^ k1;
  x0 += k0; x1 += k1;
#define TFR(r) { x0 += x1; x1 = (x1 << (r)) | (x1 >> (32 - (r))); x1 ^= x0; }
  TFR(13) TFR(15) TFR(26) TFR(6)  x0 += k1;  x1 += ks2 + 1u;
  TFR(17) TFR(29) TFR(16) TFR(24) x0 += ks2; x1 += k0 + 2u;
  TFR(13) TFR(15) TFR(26) TFR(6)  x0 += k0;  x1 += k1 + 3u;
  TFR(17) TFR(29) TFR(16) TFR(24) x0 += k1;  x1 += ks2 + 4u;
  TFR(13) TFR(15) TFR(26) TFR(6)  x0 += ks2; x1 += k0 + 5u;
#undef TFR
  o0 = x0; o1 = x1;
}
static __device__ __forceinline__ float bits_to_unif(unsigned b) {
  return __uint_as_float((b >> 9) | 0x3f800000u) - 1.0f;
}
static __device__ __forceinline__ void bnd_rand(int pt, float &xb1, float &xb2,
                                                unsigned &zbit) {
  unsigned a0, a1, b0, b1;
  tf2x32(0u, 22u, 0u, 2u, a0, b0);
  tf2x32(0u, 22u, 1u, 3u, a1, b1);
  unsigned f0, f1, zf, o0_, o1_;
  unsigned jj0 = 2u * (unsigned)pt, jj1 = jj0 + 1u;
  if (jj0 < 4096u) { tf2x32(a0, a1, jj0,         jj0 + 4096u, o0_, o1_); f0 = o0_; }
  else             { tf2x32(a0, a1, jj0 - 4096u, jj0,         o0_, o1_); f0 = o1_; }
  if (jj1 < 4096u) { tf2x32(a0, a1, jj1,         jj1 + 4096u, o0_, o1_); f1 = o0_; }
  else             { tf2x32(a0, a1, jj1 - 4096u, jj1,         o0_, o1_); f1 = o1_; }
  if (pt < 2048)   { tf2x32(b0, b1, (unsigned)pt,         (unsigned)pt + 2048u, o0_, o1_); zf = o0_; }
  else             { tf2x32(b0, b1, (unsigned)pt - 2048u, (unsigned)pt,         o0_, o1_); zf = o1_; }
  xb1 = bits_to_unif(f0); xb2 = bits_to_unif(f1); zbit = zf & 1u;
}

// ---------------- packed jet composition (two jets at once), SCALED -------
// lanes compute two independent neurons' jets: component .x and .y.
// Elementwise ops lower to v_pk_fma_f32 / v_pk_mul_f32.
static __device__ __forceinline__ void activate_jet2(f32x2 q[NCH]) {
  const float PI1 = 3.14159265358979323846f;
  float hx = q[0].x - floorf(q[0].x);
  float hy = q[0].y - floorf(q[0].y);
  f32x2 sv, cv;
  sv.x = __builtin_amdgcn_sinf(hx); sv.y = __builtin_amdgcn_sinf(hy);
  cv.x = __builtin_amdgcn_cosf(hx); cv.y = __builtin_amdgcn_cosf(hy);
  f32x2 p1 = PI1 * cv;
  f32x2 p2 = (-2.0f * PI1 * PI1) * sv;
  f32x2 p3 = (-4.0f * PI1 * PI1 * PI1) * cv;
  f32x2 p2s = p2 * 9.765625e-4f;        // p2 * 2^-10
  f32x2 p2t = p2 * 0.015625f;           // p2 * 2^-6
  f32x2 p3t = p3 * 1.52587890625e-5f;   // p3 * 2^-16
  f32x2 g0 = q[1], g1 = q[2], g2 = q[3], g3 = q[4];
  f32x2 s_tx = q[5], s_ty = q[6], s_tz = q[7], s_xx = q[8], s_xy = q[9],
        s_xz = q[10], s_yy = q[11], s_yz = q[12], s_zz = q[13];
  f32x2 T0 = q[14], T1 = q[15], T2 = q[16], T3 = q[17], T4 = q[18],
        T5 = q[19], T6 = q[20], T7 = q[21], T8 = q[22];
  q[0] = 0.5f * sv;
  q[1] = p1 * g0; q[2] = p1 * g1; q[3] = p1 * g2; q[4] = p1 * g3;
  q[5]  = p2s * g0 * g1 + p1 * s_tx;
  q[6]  = p2s * g0 * g2 + p1 * s_ty;
  q[7]  = p2s * g0 * g3 + p1 * s_tz;
  q[8]  = p2s * g1 * g1 + p1 * s_xx;
  q[9]  = p2s * g1 * g2 + p1 * s_xy;
  q[10] = p2s * g1 * g3 + p1 * s_xz;
  q[11] = p2s * g2 * g2 + p1 * s_yy;
  q[12] = p2s * g2 * g3 + p1 * s_yz;
  q[13] = p2s * g3 * g3 + p1 * s_zz;
  q[14] = p3t * g1 * g1 * g1 + p2t * (3.0f * s_xx * g1)              + p1 * T0;
  q[15] = p3t * g2 * g1 * g1 + p2t * (2.0f * s_xy * g1 + s_xx * g2)  + p1 * T1;
  q[16] = p3t * g3 * g1 * g1 + p2t * (2.0f * s_xz * g1 + s_xx * g3)  + p1 * T2;
  q[17] = p3t * g1 * g2 * g2 + p2t * (2.0f * s_xy * g2 + s_yy * g1)  + p1 * T3;
  q[18] = p3t * g2 * g2 * g2 + p2t * (3.0f * s_yy * g2)              + p1 * T4;
  q[19] = p3t * g3 * g2 * g2 + p2t * (2.0f * s_yz * g2 + s_yy * g3)  + p1 * T5;
  q[20] = p3t * g1 * g3 * g3 + p2t * (2.0f * s_xz * g3 + s_zz * g1)  + p1 * T6;
  q[21] = p3t * g2 * g3 * g3 + p2t * (2.0f * s_yz * g3 + s_zz * g2)  + p1 * T7;
  q[22] = p3t * g3 * g3 * g3 + p2t * (3.0f * s_zz * g3)              + p1 * T8;
  float bx = q[23].x - floorf(q[23].x);
  float by = q[23].y - floorf(q[23].y);
  q[23].x = 0.5f * __builtin_amdgcn_sinf(bx);
  q[23].y = 0.5f * __builtin_amdgcn_sinf(by);
}

// k-slot permutation: neuron j sits at slot s = 32*(j>>5) + 2*(j&15) + ((j>>4)&1)
// With s = ks*32 + quad*8 + e:  j = 32*ks + 16*(e&1) + 4*quad + (e>>1)
// ---------------- prep: weights as B-operand (single fp16) + out=0 --------
// wsh: [l][nt(8)][ks(4)][nl(16)][quad(4)][e(8)]  (fp16 bits)
// aoh: [ks(4)][nl(16)][quad(4)][e(8)]
__global__ __launch_bounds__(256) void prep_kernel(
    const float* __restrict__ W_hid, const float* __restrict__ W_out,
    unsigned short* __restrict__ wsh, unsigned short* __restrict__ aoh,
    float* __restrict__ out) {
  int b = blockIdx.x;
  if (b == 0 && threadIdx.x == 0) out[0] = 0.0f;
  if (b < 320) {
    int idx = b * 256 + threadIdx.x;          // [l][nt][ks][nl][quad][e]
    int l = idx >> 14, r = idx & 16383;
    int nt = r >> 11, r2 = r & 2047;
    int ks = r2 >> 9, r3 = r2 & 511;
    int nl = r3 >> 5, r4 = r3 & 31;
    int quad = r4 >> 3, e = r4 & 7;
    int jin  = 32 * ks + 16 * (e & 1) + 4 * quad + (e >> 1);
    int jout = nt * 16 + nl;
    wsh[idx] = f2h_bits(W_hid[(l << 14) + (jin << 7) + jout]);
  } else {
    int idx = (b - 320) * 256 + threadIdx.x;  // 0..2047: [ks][nl][quad][e]
    int ks = idx >> 9, r3 = idx & 511;
    int nl = r3 >> 5, r4 = r3 & 31;
    int quad = r4 >> 3, e = r4 & 7;
    int jin = 32 * ks + 16 * (e & 1) + 4 * quad + (e >> 1);
    aoh[idx] = f2h_bits((nl < 4) ? W_out[jin * 4 + nl] : 0.0f);
  }
}

// ---------------- main kernel ----------------
// LDS 27648 B: ONE jet plane (96 rows x 136 fp16) + Osm (384 f32).
// In-place plane update, 2 barriers/layer. RNG scalarized (SALU threefry).
// Packed f32x2 activation (v_pk_fma_f32) computes both neurons' jets at once.
__global__ __launch_bounds__(BS, 3) void pinn_kernel(
    const float* __restrict__ inputs, const float* __restrict__ y_true,
    const float* __restrict__ W_in,  const float* __restrict__ b_in,
    const float* __restrict__ b_hid, const float* __restrict__ b_out,
    const unsigned short* __restrict__ wsh,
    const unsigned short* __restrict__ aoh,
    float* __restrict__ out)
{
  __shared__ __align__(16) unsigned char smem[27648];
  _Float16* plane = (_Float16*)smem;
  float* Osm = (float*)(smem + OSM_OFF);

  const int t    = threadIdx.x;
  const int wave = t >> 6;
  const int lane = t & 63;
  const int q    = lane >> 4;          // quad = point p in C-layout
  const int nl   = lane & 15;
  const int P    = 16 * wave + nl;     // k-slot pair id for jet writes
  const int ja   = 32 * wave + nl;     // neuron of n-tile 2*wave
  const int jb   = ja + 16;            // neuron of n-tile 2*wave+1
  const int pt0  = blockIdx.x * PPB;

  const half8* wh8 = (const half8*)wsh;
  const half8* oh8 = (const half8*)aoh;

  // prefetch layer-0 weights (no dependence on anything)
  half8 wr[2][8];
#pragma unroll
  for (int z = 0; z < 8; ++z) {
    int i = z >> 2, ks = z & 3;
    wr[0][z] = wh8[((2 * wave + i) * 4 + ks) * 64 + nl * 4 + q];
  }

  // ---- layer 1 (4 -> 128): thread (p1 = wave, P1 = lane) -> neurons j1a,j1b
  {
    const int p1 = t >> 6;
    const int P1 = lane;
    const int j1a = 32 * (P1 >> 4) + (P1 & 15), j1b = j1a + 16;
    const int spt = __builtin_amdgcn_readfirstlane(pt0 + p1);
    float xb1, xb2; unsigned zbit;
    bnd_rand(spt, xb1, xb2, zbit);     // scalar-pipe threefry
    float x_t = inputs[spt * 4 + 0], x_x = inputs[spt * 4 + 1];
    float x_y = inputs[spt * 4 + 2], x_z = inputs[spt * 4 + 3];
    float zbf = (float)zbit;
    f32x2 Q[NCH];
    f32x2 w0 = {W_in[0 * DD + j1a], W_in[0 * DD + j1b]};
    f32x2 w1 = {W_in[1 * DD + j1a], W_in[1 * DD + j1b]};
    f32x2 w2 = {W_in[2 * DD + j1a], W_in[2 * DD + j1b]};
    f32x2 w3 = {W_in[3 * DD + j1a], W_in[3 * DD + j1b]};
    f32x2 bb = {b_in[j1a], b_in[j1b]};
    Q[0] = bb + x_t * w0 + x_x * w1 + x_y * w2 + x_z * w3;
    Q[1] = w0; Q[2] = w1; Q[3] = w2; Q[4] = w3;
#pragma unroll
    for (int c = 5; c < 23; ++c) Q[c] = (f32x2)0.0f;
    Q[23] = bb + x_t * w0 + xb1 * w1 + xb2 * w2 + zbf * w3;
    activate_jet2(Q);
    unsigned* dw = (unsigned*)plane;
#pragma unroll
    for (int c = 0; c < NCH; ++c)
      dw[ROWM(p1, c) * WPW + P1] = pk2(Q[c].x, Q[c].y);
  }
  __syncthreads();

  // ---- hidden layers: flipped GEMM M=96(jets) x N=128(neurons) x K=128
  for (int l = 0; l < NHID; ++l) {
    const half8* src = (const half8*)plane;
    unsigned* dstw = (unsigned*)plane;

    f32x4 acc[6][2];
#pragma unroll
    for (int mt = 0; mt < 6; ++mt) { acc[mt][0] = (f32x4)0.0f; acc[mt][1] = (f32x4)0.0f; }

#pragma unroll
    for (int ks = 0; ks < 4; ++ks) {
      half8 a[6];
#pragma unroll
      for (int mt = 0; mt < 6; ++mt)
        a[mt] = src[(16 * mt + nl) * WP8 + ks * 4 + q];
#pragma unroll
      for (int mt = 0; mt < 6; ++mt)
#pragma unroll
        for (int i = 0; i < 2; ++i)
          acc[mt][i] = __builtin_amdgcn_mfma_f32_16x16x32_f16(a[mt], wr[l & 1][i * 4 + ks], acc[mt][i], 0, 0, 0);
    }

    // prefetch next layer's weights (global; overlaps activation)
    if (l + 1 < NHID) {
#pragma unroll
      for (int z = 0; z < 8; ++z) {
        int i = z >> 2, ks = z & 3;
        wr[(l + 1) & 1][z] = wh8[(((l + 1) * 8 + 2 * wave + i) * 4 + ks) * 64 + nl * 4 + q];
      }
    }
    __syncthreads();   // (1) all waves' plane reads complete -> in-place safe

    // packed in-register activation: both neurons (ja, jb) at once
    f32x2 Q[NCH];
#pragma unroll
    for (int mt = 0; mt < 6; ++mt)
#pragma unroll
      for (int r = 0; r < 4; ++r) {
        f32x2 v = {acc[mt][0][r], acc[mt][1][r]};
        Q[4 * mt + r] = v;
      }
    f32x2 bv = {b_hid[l * DD + ja], b_hid[l * DD + jb]};
    Q[0] += bv; Q[23] += bv;
    activate_jet2(Q);
#pragma unroll
    for (int c = 0; c < NCH; ++c)
      dstw[ROWM(q, c) * WPW + P] = pk2(Q[c].x, Q[c].y);
    __syncthreads();   // (2) new plane visible to all waves
  }

  // ---- output layer: A = final jets (plane), B = W_out padded (N=16)
  {
    const half8* src = (const half8*)plane;
    if (wave < 3) {
      f32x4 acc2[2];
      acc2[0] = (f32x4)0.0f; acc2[1] = (f32x4)0.0f;
#pragma unroll
      for (int ks = 0; ks < 4; ++ks) {
        half8 a0 = src[(16 * (2 * wave)     + nl) * WP8 + ks * 4 + q];
        half8 a1 = src[(16 * (2 * wave + 1) + nl) * WP8 + ks * 4 + q];
        half8 oh = oh8[ks * 64 + nl * 4 + q];
        acc2[0] = __builtin_amdgcn_mfma_f32_16x16x32_f16(a0, oh, acc2[0], 0, 0, 0);
        acc2[1] = __builtin_amdgcn_mfma_f32_16x16x32_f16(a1, oh, acc2[1], 0, 0, 0);
      }
      if (nl < 4) {
#pragma unroll
        for (int i = 0; i < 2; ++i)
#pragma unroll
          for (int r = 0; r < 4; ++r)
            Osm[(q * NCH + 4 * (2 * wave + i) + r) * 4 + nl] = acc2[i][r];
      }
    }
  }
  __syncthreads();     // Osm ready

  // ---- loss epilogue: lane 0 of wave pp handles point pp (4 waves busy)
  if (lane == 0) {
    const int pp = wave;
    const int ptt = __builtin_amdgcn_readfirstlane(pt0 + pp);
    float xb1_, xb2_; unsigned zbit;
    bnd_rand(ptt, xb1_, xb2_, zbit);
    const float Ttrue = zbit ? -0.5f : 0.5f;
    const float SEC  = SS_INV;                              // 2nd-deriv unscale
    const float SCT  = 8.36660026534e-04f * ST_INV;         // sqrt(Pr/Ra)*2^16
    const float KAPS = 1.19522860933e-03f * SS_INV;         // kappa*2^10
    float bo0 = b_out[0], bo1 = b_out[1], bo2 = b_out[2], bo3 = b_out[3];
#define OO(o, c) Osm[(pp * NCH + (c)) * 4 + (o)]
    float u  = OO(0, 0) + bo0, v_ = OO(1, 0) + bo1, w_ = OO(2, 0) + bo2;
    float ux = OO(0, 2), uy = OO(0, 3), uz = OO(0, 4);
    float vx = OO(1, 2), vy = OO(1, 3), vz = OO(1, 4);
    float wx = OO(2, 2), wy = OO(2, 3), wz = OO(2, 4);
    float Tt = OO(3, 1), Tx = OO(3, 2), Ty = OO(3, 3), Tz = OO(3, 4);

    float hu = OO(2, 6) - OO(1, 7)
             + u  * (OO(2, 9)  - OO(1, 10))
             + v_ * (OO(2, 11) - OO(1, 12))
             + w_ * (OO(2, 12) - OO(1, 13));
    float NSEu = SEC * hu
               - (wy - vz) * ux - (uz - wx) * uy - (vx - uy) * uz
               - SCT * (OO(2, 15) - OO(1, 16) + OO(2, 18) - OO(1, 19) + OO(2, 21) - OO(1, 22))
               - Ty;
    float hv = OO(0, 7) - OO(2, 5)
             + u  * (OO(0, 10) - OO(2, 8))
             + v_ * (OO(0, 12) - OO(2, 9))
             + w_ * (OO(0, 13) - OO(2, 10));
    float NSEv = SEC * hv
               - (wy - vz) * vx - (uz - wx) * vy - (vx - uy) * vz
               - SCT * (OO(0, 16) - OO(2, 14) + OO(0, 19) - OO(2, 17) + OO(0, 22) - OO(2, 20))
               + Tx;
    float hw = OO(1, 5) - OO(0, 6)
             + u  * (OO(1, 8)  - OO(0, 9))
             + v_ * (OO(1, 9)  - OO(0, 11))
             + w_ * (OO(1, 10) - OO(0, 12));
    float NSEw = SEC * hw
               - (wy - vz) * wx - (uz - wx) * wy - (vx - uy) * wz
               - SCT * (OO(1, 14) - OO(0, 15) + OO(1, 17) - OO(0, 18) + OO(1, 20) - OO(0, 21));

    float EE = Tt + u * Tx + v_ * Ty + w_ * Tz
             - KAPS * (OO(3, 8) + OO(3, 11) + OO(3, 13));

    float conti = ux + vy + wz;
    const float* yt = y_true + ptt * 4;
    float d0 = u - yt[0], d1 = v_ - yt[1], d2 = w_ - yt[2];
    float dT = Ttrue - (OO(3, 23) + bo3);
#undef OO
    const float invN  = 1.0f / (float)NPTS;
    const float inv3N = 1.0f / (3.0f * (float)NPTS);
    float part = (d0 * d0 + d1 * d1 + d2 * d2) * inv3N
               + conti * conti * invN
               + (NSEu * NSEu + NSEv * NSEv + NSEw * NSEw) * inv3N
               + EE * EE * invN
               + dT * dT * invN;
    atomicAdd(out, part);
  }
}

extern "C" void kernel_launch(void* const* d_in, const int* in_sizes, int n_in,
                              void* d_out, int out_size, void* d_ws, size_t ws_size,
                              hipStream_t stream) {
  const float* inputs = (const float*)d_in[0];
  const float* y_true = (const float*)d_in[1];
  const float* W_in   = (const float*)d_in[2];
  const float* b_in   = (const float*)d_in[3];
  const float* W_hid  = (const float*)d_in[4];
  const float* b_hid  = (const float*)d_in[5];
  const float* W_out  = (const float*)d_in[6];
  const float* b_out  = (const float*)d_in[7];
  float* out = (float*)d_out;

  unsigned char* ws = (unsigned char*)d_ws;
  unsigned short* wsh = (unsigned short*)(ws);             // 163840 B
  unsigned short* aoh = (unsigned short*)(ws + 163840);    // 4096 B

  prep_kernel<<<328, 256, 0, stream>>>(W_hid, W_out, wsh, aoh, out);
  pinn_kernel<<<NPTS / PPB, BS, 0, stream>>>(inputs, y_true, W_in, b_in,
                                             b_hid, b_out, wsh, aoh, out);
}

// Round 13
// 94.376 us; speedup vs baseline: 1.4458x; 1.4458x over previous
//
#include <hip/hip_runtime.h>
#include <math.h>

#define NPTS 4096
#define DD   128
#define NCH  24
#define NHID 5
#define PPB  4            // points per block (= quad)
#define BS   256
#define WP8  17           // jet plane row stride in half8 units (136 fp16)
#define WPW  68           // jet plane row stride in u32 units
#define PLSZ 26112        // one jet plane: 96 rows x 272 B
#define OSM_OFF 52224     // Osm after the two planes
// jet row for (point p, channel c)
#define ROWM(p,c) (16*((c)>>2) + 4*(p) + ((c)&3))

typedef __attribute__((ext_vector_type(8))) _Float16 half8;
typedef __attribute__((ext_vector_type(2))) __fp16 fp16x2;
typedef __attribute__((ext_vector_type(4))) float f32x4;

// channel scales: ch0-4,23: 1; ch5-13 (2nd): 2^-10; ch14-22 (3rd): 2^-16
#define SS_INV 1024.0f
#define ST_INV 65536.0f

static __device__ __forceinline__ unsigned short f2h_bits(float x) {
  _Float16 h = (_Float16)x; unsigned short u; __builtin_memcpy(&u, &h, 2); return u;
}
static __device__ __forceinline__ unsigned pk2(float a, float b) {
  fp16x2 h = __builtin_amdgcn_cvt_pkrtz(a, b);   // 1 inst, packs 2 fp16 (RTZ)
  unsigned u; __builtin_memcpy(&u, &h, 4); return u;
}

// ---------------- threefry2x32 (matches JAX's PRNG) ----------------
static __device__ __forceinline__ void tf2x32(unsigned k0, unsigned k1,
                                              unsigned x0, unsigned x1,
                                              unsigned &o0, unsigned &o1) {
  unsigned ks2 = 0x1BD11BDAu ^ k0 ^ k1;
  x0 += k0; x1 += k1;
#define TFR(r) { x0 += x1; x1 = (x1 << (r)) | (x1 >> (32 - (r))); x1 ^= x0; }
  TFR(13) TFR(15) TFR(26) TFR(6)  x0 += k1;  x1 += ks2 + 1u;
  TFR(17) TFR(29) TFR(16) TFR(24) x0 += ks2; x1 += k0 + 2u;
  TFR(13) TFR(15) TFR(26) TFR(6)  x0 += k0;  x1 += k1 + 3u;
  TFR(17) TFR(29) TFR(16) TFR(24) x0 += k1;  x1 += ks2 + 4u;
  TFR(13) TFR(15) TFR(26) TFR(6)  x0 += ks2; x1 += k0 + 5u;
#undef TFR
  o0 = x0; o1 = x1;
}
static __device__ __forceinline__ float bits_to_unif(unsigned b) {
  return __uint_as_float((b >> 9) | 0x3f800000u) - 1.0f;
}
static __device__ __forceinline__ void bnd_rand(int pt, float &xb1, float &xb2,
                                                unsigned &zbit) {
  unsigned a0, a1, b0, b1;
  tf2x32(0u, 22u, 0u, 2u, a0, b0);
  tf2x32(0u, 22u, 1u, 3u, a1, b1);
  unsigned f0, f1, zf, o0_, o1_;
  unsigned jj0 = 2u * (unsigned)pt, jj1 = jj0 + 1u;
  if (jj0 < 4096u) { tf2x32(a0, a1, jj0,         jj0 + 4096u, o0_, o1_); f0 = o0_; }
  else             { tf2x32(a0, a1, jj0 - 4096u, jj0,         o0_, o1_); f0 = o1_; }
  if (jj1 < 4096u) { tf2x32(a0, a1, jj1,         jj1 + 4096u, o0_, o1_); f1 = o0_; }
  else             { tf2x32(a0, a1, jj1 - 4096u, jj1,         o0_, o1_); f1 = o1_; }
  if (pt < 2048)   { tf2x32(b0, b1, (unsigned)pt,         (unsigned)pt + 2048u, o0_, o1_); zf = o0_; }
  else             { tf2x32(b0, b1, (unsigned)pt - 2048u, (unsigned)pt,         o0_, o1_); zf = o1_; }
  xb1 = bits_to_unif(f0); xb2 = bits_to_unif(f1); zbit = zf & 1u;
}

// ---------------- jet composition, SCALED convention ----------------
static __device__ __forceinline__ void activate_jet(float q[NCH]) {
  const float PI1 = 3.14159265358979323846f;
  float hr = q[0] - floorf(q[0]);
  float sv = __builtin_amdgcn_sinf(hr);
  float cv = __builtin_amdgcn_cosf(hr);
  float p1 = PI1 * cv;
  float p2  = -2.0f * PI1 * PI1 * sv;
  float p3  = -4.0f * PI1 * PI1 * PI1 * cv;
  float p2s = p2 * 9.765625e-4f;        // p2 * 2^-10
  float p2t = p2 * 0.015625f;           // p2 * 2^-6
  float p3t = p3 * 1.52587890625e-5f;   // p3 * 2^-16
  float g0 = q[1], g1 = q[2], g2 = q[3], g3 = q[4];
  float s_tx = q[5], s_ty = q[6], s_tz = q[7], s_xx = q[8], s_xy = q[9],
        s_xz = q[10], s_yy = q[11], s_yz = q[12], s_zz = q[13];
  float T0 = q[14], T1 = q[15], T2 = q[16], T3 = q[17], T4 = q[18],
        T5 = q[19], T6 = q[20], T7 = q[21], T8 = q[22];
  q[0] = 0.5f * sv;
  q[1] = p1 * g0; q[2] = p1 * g1; q[3] = p1 * g2; q[4] = p1 * g3;
  q[5]  = p2s * g0 * g1 + p1 * s_tx;
  q[6]  = p2s * g0 * g2 + p1 * s_ty;
  q[7]  = p2s * g0 * g3 + p1 * s_tz;
  q[8]  = p2s * g1 * g1 + p1 * s_xx;
  q[9]  = p2s * g1 * g2 + p1 * s_xy;
  q[10] = p2s * g1 * g3 + p1 * s_xz;
  q[11] = p2s * g2 * g2 + p1 * s_yy;
  q[12] = p2s * g2 * g3 + p1 * s_yz;
  q[13] = p2s * g3 * g3 + p1 * s_zz;
  q[14] = p3t * g1 * g1 * g1 + p2t * (3.0f * s_xx * g1)              + p1 * T0;
  q[15] = p3t * g2 * g1 * g1 + p2t * (2.0f * s_xy * g1 + s_xx * g2)  + p1 * T1;
  q[16] = p3t * g3 * g1 * g1 + p2t * (2.0f * s_xz * g1 + s_xx * g3)  + p1 * T2;
  q[17] = p3t * g1 * g2 * g2 + p2t * (2.0f * s_xy * g2 + s_yy * g1)  + p1 * T3;
  q[18] = p3t * g2 * g2 * g2 + p2t * (3.0f * s_yy * g2)              + p1 * T4;
  q[19] = p3t * g3 * g2 * g2 + p2t * (2.0f * s_yz * g2 + s_yy * g3)  + p1 * T5;
  q[20] = p3t * g1 * g3 * g3 + p2t * (2.0f * s_xz * g3 + s_zz * g1)  + p1 * T6;
  q[21] = p3t * g2 * g3 * g3 + p2t * (2.0f * s_yz * g3 + s_zz * g2)  + p1 * T7;
  q[22] = p3t * g3 * g3 * g3 + p2t * (3.0f * s_zz * g3)              + p1 * T8;
  float br = q[23] - floorf(q[23]);
  q[23] = 0.5f * __builtin_amdgcn_sinf(br);
}

// k-slot permutation: neuron j sits at slot s = 32*(j>>5) + 2*(j&15) + ((j>>4)&1)
// With s = ks*32 + quad*8 + e:  j = 32*ks + 16*(e&1) + 4*quad + (e>>1)
// ---------------- prep: weights as B-operand (single fp16) + RNG + out=0 --
// wsh: [l][nt(8)][ks(4)][nl(16)][quad(4)][e(8)]  (fp16 bits)
// aoh: [ks(4)][nl(16)][quad(4)][e(8)]
__global__ __launch_bounds__(256) void prep_kernel(
    const float* __restrict__ W_hid, const float* __restrict__ W_out,
    unsigned short* __restrict__ wsh, unsigned short* __restrict__ aoh,
    float4* __restrict__ rnd, float* __restrict__ out) {
  int b = blockIdx.x;
  if (b == 0 && threadIdx.x == 0) out[0] = 0.0f;
  if (b < 320) {
    int idx = b * 256 + threadIdx.x;          // [l][nt][ks][nl][quad][e]
    int l = idx >> 14, r = idx & 16383;
    int nt = r >> 11, r2 = r & 2047;
    int ks = r2 >> 9, r3 = r2 & 511;
    int nl = r3 >> 5, r4 = r3 & 31;
    int quad = r4 >> 3, e = r4 & 7;
    int jin  = 32 * ks + 16 * (e & 1) + 4 * quad + (e >> 1);
    int jout = nt * 16 + nl;
    wsh[idx] = f2h_bits(W_hid[(l << 14) + (jin << 7) + jout]);
  } else if (b < 328) {
    int idx = (b - 320) * 256 + threadIdx.x;  // 0..2047: [ks][nl][quad][e]
    int ks = idx >> 9, r3 = idx & 511;
    int nl = r3 >> 5, r4 = r3 & 31;
    int quad = r4 >> 3, e = r4 & 7;
    int jin = 32 * ks + 16 * (e & 1) + 4 * quad + (e >> 1);
    aoh[idx] = f2h_bits((nl < 4) ? W_out[jin * 4 + nl] : 0.0f);
  } else {
    int pt = (b - 328) * 256 + threadIdx.x;
    float xb1, xb2; unsigned zbit;
    bnd_rand(pt, xb1, xb2, zbit);
    rnd[pt] = make_float4(xb1, xb2, (float)zbit, zbit ? -0.5f : 0.5f);
  }
}

// ---------------- main kernel ----------------
// LDS 53760 B: two jet planes (A-operand layout, 96 rows x 136 fp16) + Osm.
// Flipped GEMM: A=jets(M=96), B=W fp16 (N=128). One barrier per layer;
// in-register activation (two independent scalar chains for ILP);
// next-layer weights prefetched into VGPRs.
__global__ __launch_bounds__(BS, 3) void pinn_kernel(
    const float* __restrict__ inputs, const float* __restrict__ y_true,
    const float* __restrict__ W_in,  const float* __restrict__ b_in,
    const float* __restrict__ b_hid, const float* __restrict__ b_out,
    const unsigned short* __restrict__ wsh,
    const unsigned short* __restrict__ aoh,
    const float4* __restrict__ rnd,
    float* __restrict__ out)
{
  __shared__ __align__(16) unsigned char smem[53760];
  _Float16* plane0 = (_Float16*)smem;
  _Float16* plane1 = (_Float16*)(smem + PLSZ);
  float* Osm = (float*)(smem + OSM_OFF);

  const int t    = threadIdx.x;
  const int wave = t >> 6;
  const int lane = t & 63;
  const int q    = lane >> 4;          // quad = point p in C-layout
  const int nl   = lane & 15;
  const int P    = 16 * wave + nl;     // k-slot pair id for jet writes
  const int ja   = 32 * wave + nl;     // neuron of n-tile 2*wave
  const int jb   = ja + 16;            // neuron of n-tile 2*wave+1
  const int pt0  = blockIdx.x * PPB;

  const half8* wh8 = (const half8*)wsh;
  const half8* oh8 = (const half8*)aoh;

  // prefetch layer-0 weights (no dependence on anything)
  half8 wr[2][8];
#pragma unroll
  for (int z = 0; z < 8; ++z) {
    int i = z >> 2, ks = z & 3;
    wr[0][z] = wh8[((2 * wave + i) * 4 + ks) * 64 + nl * 4 + q];
  }

  // ---- layer 1 (4 -> 128): thread (p1 = wave, P1 = lane) -> neurons j1a,j1b
  {
    const int p1 = t >> 6;
    const int P1 = lane;
    const int j1a = 32 * (P1 >> 4) + (P1 & 15), j1b = j1a + 16;
    const int pt = pt0 + p1;
    float4 rv = rnd[pt];
    float x_t = inputs[pt * 4 + 0], x_x = inputs[pt * 4 + 1];
    float x_y = inputs[pt * 4 + 2], x_z = inputs[pt * 4 + 3];
    float q0[NCH], q1[NCH];
#pragma unroll
    for (int h = 0; h < 2; ++h) {
      int jj = h ? j1b : j1a;
      float* qq = h ? q1 : q0;
      float w0 = W_in[0 * DD + jj], w1 = W_in[1 * DD + jj],
            w2 = W_in[2 * DD + jj], w3 = W_in[3 * DD + jj];
      float bb = b_in[jj];
      qq[0] = bb + x_t * w0 + x_x * w1 + x_y * w2 + x_z * w3;
      qq[1] = w0; qq[2] = w1; qq[3] = w2; qq[4] = w3;
#pragma unroll
      for (int c = 5; c < 23; ++c) qq[c] = 0.0f;
      qq[23] = bb + x_t * w0 + rv.x * w1 + rv.y * w2 + rv.z * w3;
      activate_jet(qq);
    }
    unsigned* dw = (unsigned*)plane0;
#pragma unroll
    for (int c = 0; c < NCH; ++c)
      dw[ROWM(p1, c) * WPW + P1] = pk2(q0[c], q1[c]);
  }
  __syncthreads();

  // ---- hidden layers: flipped GEMM M=96(jets) x N=128(neurons) x K=128
#pragma unroll
  for (int l = 0; l < NHID; ++l) {
    const half8* src = (const half8*)((l & 1) ? plane1 : plane0);
    unsigned* dstw = (unsigned*)((l & 1) ? plane0 : plane1);

    f32x4 acc[6][2];
#pragma unroll
    for (int mt = 0; mt < 6; ++mt) { acc[mt][0] = (f32x4)0.0f; acc[mt][1] = (f32x4)0.0f; }

#pragma unroll
    for (int ks = 0; ks < 4; ++ks) {
      half8 a[6];
#pragma unroll
      for (int mt = 0; mt < 6; ++mt)
        a[mt] = src[(16 * mt + nl) * WP8 + ks * 4 + q];
#pragma unroll
      for (int mt = 0; mt < 6; ++mt)
#pragma unroll
        for (int i = 0; i < 2; ++i)
          acc[mt][i] = __builtin_amdgcn_mfma_f32_16x16x32_f16(a[mt], wr[l & 1][i * 4 + ks], acc[mt][i], 0, 0, 0);
    }

    // prefetch next layer's weights (overlaps with activation VALU)
    if (l + 1 < NHID) {
#pragma unroll
      for (int z = 0; z < 8; ++z) {
        int i = z >> 2, ks = z & 3;
        wr[(l + 1) & 1][z] = wh8[(((l + 1) * 8 + 2 * wave + i) * 4 + ks) * 64 + nl * 4 + q];
      }
    }

    // in-register activation: lane holds all 24 channels of point q for ja, jb
    float qa[NCH], qb[NCH];
#pragma unroll
    for (int mt = 0; mt < 6; ++mt)
#pragma unroll
      for (int r = 0; r < 4; ++r) {
        qa[4 * mt + r] = acc[mt][0][r];
        qb[4 * mt + r] = acc[mt][1][r];
      }
    float ba = b_hid[l * DD + ja], bb_ = b_hid[l * DD + jb];
    qa[0] += ba; qa[23] += ba;
    qb[0] += bb_; qb[23] += bb_;
    activate_jet(qa);
    activate_jet(qb);
#pragma unroll
    for (int c = 0; c < NCH; ++c)
      dstw[ROWM(q, c) * WPW + P] = pk2(qa[c], qb[c]);
    __syncthreads();   // dst plane complete; src plane reads all done
  }

  // ---- output layer: A = final jets (plane1), B = W_out padded (N=16)
  {
    const half8* src = (const half8*)plane1;   // NHID odd -> final in plane1
    if (wave < 3) {
      f32x4 acc2[2];
      acc2[0] = (f32x4)0.0f; acc2[1] = (f32x4)0.0f;
#pragma unroll
      for (int ks = 0; ks < 4; ++ks) {
        half8 a0 = src[(16 * (2 * wave)     + nl) * WP8 + ks * 4 + q];
        half8 a1 = src[(16 * (2 * wave + 1) + nl) * WP8 + ks * 4 + q];
        half8 oh = oh8[ks * 64 + nl * 4 + q];
        acc2[0] = __builtin_amdgcn_mfma_f32_16x16x32_f16(a0, oh, acc2[0], 0, 0, 0);
        acc2[1] = __builtin_amdgcn_mfma_f32_16x16x32_f16(a1, oh, acc2[1], 0, 0, 0);
      }
      if (nl < 4) {
#pragma unroll
        for (int i = 0; i < 2; ++i)
#pragma unroll
          for (int r = 0; r < 4; ++r)
            Osm[(q * NCH + 4 * (2 * wave + i) + r) * 4 + nl] = acc2[i][r];
      }
    }
  }
  __syncthreads();     // Osm ready

  // ---- loss epilogue: threads 0..3 (one point each)
  if (t < PPB) {
    const int pp = t;
    const int ptt = pt0 + pp;
    const float Ttrue = rnd[ptt].w;
    const float SEC  = SS_INV;                              // 2nd-deriv unscale
    const float SCT  = 8.36660026534e-04f * ST_INV;         // sqrt(Pr/Ra)*2^16
    const float KAPS = 1.19522860933e-03f * SS_INV;         // kappa*2^10
    float bo0 = b_out[0], bo1 = b_out[1], bo2 = b_out[2], bo3 = b_out[3];
#define OO(o, c) Osm[(pp * NCH + (c)) * 4 + (o)]
    float u  = OO(0, 0) + bo0, v_ = OO(1, 0) + bo1, w_ = OO(2, 0) + bo2;
    float ux = OO(0, 2), uy = OO(0, 3), uz = OO(0, 4);
    float vx = OO(1, 2), vy = OO(1, 3), vz = OO(1, 4);
    float wx = OO(2, 2), wy = OO(2, 3), wz = OO(2, 4);
    float Tt = OO(3, 1), Tx = OO(3, 2), Ty = OO(3, 3), Tz = OO(3, 4);

    float hu = OO(2, 6) - OO(1, 7)
             + u  * (OO(2, 9)  - OO(1, 10))
             + v_ * (OO(2, 11) - OO(1, 12))
             + w_ * (OO(2, 12) - OO(1, 13));
    float NSEu = SEC * hu
               - (wy - vz) * ux - (uz - wx) * uy - (vx - uy) * uz
               - SCT * (OO(2, 15) - OO(1, 16) + OO(2, 18) - OO(1, 19) + OO(2, 21) - OO(1, 22))
               - Ty;
    float hv = OO(0, 7) - OO(2, 5)
             + u  * (OO(0, 10) - OO(2, 8))
             + v_ * (OO(0, 12) - OO(2, 9))
             + w_ * (OO(0, 13) - OO(2, 10));
    float NSEv = SEC * hv
               - (wy - vz) * vx - (uz - wx) * vy - (vx - uy) * vz
               - SCT * (OO(0, 16) - OO(2, 14) + OO(0, 19) - OO(2, 17) + OO(0, 22) - OO(2, 20))
               + Tx;
    float hw = OO(1, 5) - OO(0, 6)
             + u  * (OO(1, 8)  - OO(0, 9))
             + v_ * (OO(1, 9)  - OO(0, 11))
             + w_ * (OO(1, 10) - OO(0, 12));
    float NSEw = SEC * hw
               - (wy - vz) * wx - (uz - wx) * wy - (vx - uy) * wz
               - SCT * (OO(1, 14) - OO(0, 15) + OO(1, 17) - OO(0, 18) + OO(1, 20) - OO(0, 21));

    float EE = Tt + u * Tx + v_ * Ty + w_ * Tz
             - KAPS * (OO(3, 8) + OO(3, 11) + OO(3, 13));

    float conti = ux + vy + wz;
    const float* yt = y_true + ptt * 4;
    float d0 = u - yt[0], d1 = v_ - yt[1], d2 = w_ - yt[2];
    float dT = Ttrue - (OO(3, 23) + bo3);
#undef OO
    const float invN  = 1.0f / (float)NPTS;
    const float inv3N = 1.0f / (3.0f * (float)NPTS);
    float part = (d0 * d0 + d1 * d1 + d2 * d2) * inv3N
               + conti * conti * invN
               + (NSEu * NSEu + NSEv * NSEv + NSEw * NSEw) * inv3N
               + EE * EE * invN
               + dT * dT * invN;
    atomicAdd(out, part);
  }
}

extern "C" void kernel_launch(void* const* d_in, const int* in_sizes, int n_in,
                              void* d_out, int out_size, void* d_ws, size_t ws_size,
                              hipStream_t stream) {
  const float* inputs = (const float*)d_in[0];
  const float* y_true = (const float*)d_in[1];
  const float* W_in   = (const float*)d_in[2];
  const float* b_in   = (const float*)d_in[3];
  const float* W_hid  = (const float*)d_in[4];
  const float* b_hid  = (const float*)d_in[5];
  const float* W_out  = (const float*)d_in[6];
  const float* b_out  = (const float*)d_in[7];
  float* out = (float*)d_out;

  unsigned char* ws = (unsigned char*)d_ws;
  unsigned short* wsh = (unsigned short*)(ws);             // 163840 B
  unsigned short* aoh = (unsigned short*)(ws + 163840);    // 4096 B
  float4*         rnd = (float4*)(ws + 167936);            // 65536 B

  prep_kernel<<<344, 256, 0, stream>>>(W_hid, W_out, wsh, aoh, rnd, out);
  pinn_kernel<<<NPTS / PPB, BS, 0, stream>>>(inputs, y_true, W_in, b_in,
                                             b_hid, b_out, wsh, aoh, rnd, out);
}